// Round 4
// baseline (7983.916 us; speedup 1.0000x reference)
//
#include <hip/hip_runtime.h>

#define Tn 64
#define Bn 512
#define Dn 512
#define Hn 2048
#define CH 16   // batch chunks, M=32 rows each
#define SL 16   // H slices, 128 cols each

typedef __attribute__((ext_vector_type(8))) short s16x8;
typedef __attribute__((ext_vector_type(4))) float f32x4;
typedef unsigned int u32;
typedef unsigned long long u64;
typedef unsigned short u16;

__device__ __forceinline__ u16 f2bf(float f) {
    u32 u = __builtin_bit_cast(u32, f);
    return (u16)((u + 0x7fffu + ((u >> 16) & 1u)) >> 16);
}
__device__ __forceinline__ float bf2f(u32 v) {
    return __builtin_bit_cast(float, v << 16);
}
__device__ __forceinline__ float tanh_fast(float x) {
    float e = __builtin_amdgcn_exp2f(x * 2.885390081777927f);
    return 1.0f - 2.0f * __builtin_amdgcn_rcpf(e + 1.0f);
}
__device__ __forceinline__ u32 agent_ld(const u32* p) {
    return __hip_atomic_load((u32*)p, __ATOMIC_RELAXED, __HIP_MEMORY_SCOPE_AGENT);
}
__device__ __forceinline__ void agent_st(u32* p, u32 v) {
    __hip_atomic_store(p, v, __ATOMIC_RELAXED, __HIP_MEMORY_SCOPE_AGENT);
}
__device__ __forceinline__ void agent_st64(u64* p, u64 v) {
    __hip_atomic_store(p, v, __ATOMIC_RELAXED, __HIP_MEMORY_SCOPE_AGENT);
}

// Pack W1 (512x2048) and W2 (2048x512), f32 row-major -> bf16 MFMA-B-fragment order:
// [ntile][ktile][lane][8], element (k,n): lane = (n%16) + 16*((k%32)/8), e = k%8.
__global__ void pack_w(const float* __restrict__ W1, const float* __restrict__ W2,
                       u16* __restrict__ w1p, u16* __restrict__ w2p) {
    const int i = blockIdx.x * 256 + threadIdx.x;
    const int e = i & 7;
    const int lane = (i >> 3) & 63;
    const int krem = ((lane >> 4) << 3) + e;
    const int ncol = lane & 15;
    {   // W1: K=512 (16 ktiles), N=2048 (128 ntiles)
        const int kt = (i >> 9) & 15, nt = i >> 13;
        const int k = (kt << 5) + krem, n = (nt << 4) + ncol;
        w1p[i] = f2bf(W1[k * Hn + n]);
    }
    {   // W2: K=2048 (64 ktiles), N=512 (32 ntiles)
        const int kt = (i >> 9) & 63, nt = i >> 15;
        const int k = (kt << 5) + krem, n = (nt << 4) + ncol;
        w2p[i] = f2bf(W2[k * Dn + n]);
    }
}

// 256 WGs = 16 chunks x 16 slices.
// MAPPING (v4 fix): bid = r*16 + h  =>  XCD = bid%8 = h%8. Slices pin to XCDs, so
// each XCD's weight working set is 2 slices = 512KB (L2-resident). Chunk exchange
// (agent scope) goes through MALL regardless of placement.
__launch_bounds__(512, 2)
__global__ void ode_v3(const float* __restrict__ y0, const float* __restrict__ tt,
                       const float* __restrict__ b1, const float* __restrict__ b2,
                       const u16* __restrict__ w1p, const u16* __restrict__ w2p,
                       float* __restrict__ out, u16* __restrict__ ybuf,
                       u16* __restrict__ kpart, u32* __restrict__ flags1,
                       u32* __restrict__ flags2) {
    __shared__ u16 lds_A[32 * 512];    // 32KB, row stride 1024B, xor-swz ((row&7)<<4)
    __shared__ u16 lds_H[32 * 128];    // 8KB,  row stride 256B,  xor-swz ((row&7)<<4)
    char* ldsAb = (char*)lds_A;
    char* ldsHb = (char*)lds_H;

    const int tid = threadIdx.x;
    const int w = tid >> 6, lane = tid & 63, l15 = lane & 15, kg = lane >> 4;
    const int bid = blockIdx.x;
    const int r = bid >> 4, h = bid & 15;   // v4: slice -> XCD affinity

    // ---- owner/reducer per-thread mapping: stripe col sc, rowpair rp ----
    const int sc = tid >> 4;                 // 0..31
    const int rp = tid & 15;                 // 0..15
    const int colg = (h << 5) + sc;
    const int brow0 = (r << 5) + 2 * rp, brow1 = brow0 + 1;
    const float b2c = b2[colg];
    float ys0 = y0[brow0 * Dn + colg];
    float ys1 = y0[brow1 * Dn + colg];
    out[brow0 * Dn + colg] = ys0;
    out[brow1 * Dn + colg] = ys1;
    float ks0 = 0.f, ks1 = 0.f, dt0 = 0.f, dt1 = 0.f;

    // ---- GEMM wave constants ----
    const int mt = w & 1;                    // m-tile (rows mt*16..)
    const int np = w >> 1;                   // 0..3
    const float bia0 = b1[(h << 7) + ((np << 1) << 4) + l15];
    const float bia1 = b1[(h << 7) + (((np << 1) + 1) << 4) + l15];
    const u16* wp1 = w1p + ((size_t)((h << 3) + (np << 1)) << 4) * 512 + (lane << 3);
    const u16* wp2 = w2p + ((size_t)(np << 3) * 64 + (h << 2)) * 512 + (lane << 3);

    const u32 arow = (u32)((mt << 4) + l15);
    const u32 abase = arow * 1024u + ((u32)kg << 4);
    const u32 aswz = (arow & 7u) << 4;
    const u32 hbase = arow * 256u + ((u32)kg << 4);
    const u32 hswz = aswz;

    u32* ybr = (u32*)(ybuf + (size_t)r * 32 * 512);
    const char* kown = (const char*)kpart + (size_t)(((r << 4) + h) << 4) * 2048;
    char* kprod = (char*)kpart + (size_t)(r << 8) * 2048;  // + (o*16+h)*2048
    u32* fl1 = flags1 + ((r << 4) << 6);     // chunk r's producer flags, 256B apart
    u32* fl2 = flags2 + ((r << 4) << 6);

    #pragma unroll 1
    for (int s = 0; s < 252; ++s) {
        // ================= stage A: yin -> lds_A =================
        if (s == 0) {
            const float4* y0c = (const float4*)(y0 + (size_t)(r << 5) * Dn);
            #pragma unroll
            for (int it = 0; it < 8; ++it) {
                const int idx = (it << 9) + tid;          // over [32 rows][128 f4]
                const float4 v = y0c[idx];
                const u32 row = (u32)idx >> 7;
                u64 pk = (u64)((u32)f2bf(v.x) | ((u32)f2bf(v.y) << 16)) |
                         ((u64)((u32)f2bf(v.z) | ((u32)f2bf(v.w) << 16)) << 32);
                const u32 dst = (row * 1024u + ((u32)(idx & 127) << 3)) ^ ((row & 7u) << 4);
                *(u64*)(ldsAb + dst) = pk;
            }
        } else {
            if (tid < 16) {
                const u32 tgt = (u32)s;
                while (agent_ld(fl2 + (tid << 6)) < tgt) __builtin_amdgcn_s_sleep(1);
            }
            __syncthreads();
            #pragma unroll
            for (int it = 0; it < 16; ++it) {
                const int j = (it << 9) + tid;            // u32 over [32 rows][256 u32]
                const u32 v = agent_ld(ybr + j);
                const u32 row = (u32)j >> 8;
                const u32 dst = ((u32)j << 2) ^ ((row & 7u) << 4);
                *(u32*)(ldsAb + dst) = v;
            }
        }
        __syncthreads();

        // ================= GEMM1: hid = tanh(A @ W1slice + b1) =================
        f32x4 a1[2];
        a1[0] = f32x4{bia0, bia0, bia0, bia0};
        a1[1] = f32x4{bia1, bia1, bia1, bia1};
        #pragma unroll
        for (int kt = 0; kt < 16; ++kt) {
            const s16x8 a = *(const s16x8*)(ldsAb + ((abase + ((u32)kt << 6)) ^ aswz));
            const s16x8 b0 = *(const s16x8*)(wp1 + ((size_t)kt << 9));
            const s16x8 b1f = *(const s16x8*)(wp1 + ((size_t)(16 + kt) << 9));
            a1[0] = __builtin_amdgcn_mfma_f32_16x16x32_bf16(a, b0, a1[0], 0, 0, 0);
            a1[1] = __builtin_amdgcn_mfma_f32_16x16x32_bf16(a, b1f, a1[1], 0, 0, 0);
        }
        #pragma unroll
        for (int n = 0; n < 2; ++n) {
            #pragma unroll
            for (int j = 0; j < 4; ++j) {
                const u32 row = (u32)((mt << 4) + (kg << 2) + j);
                const u32 col = (u32)((((np << 1) + n) << 4) + l15);
                const u32 bo = (row * 256u + (col << 1)) ^ ((row & 7u) << 4);
                *(u16*)(ldsHb + bo) = f2bf(tanh_fast(a1[n][j]));
            }
        }
        __syncthreads();

        // ================= GEMM2: partial = hid @ W2slice (K=128) =================
        f32x4 acc[8];
        #pragma unroll
        for (int c = 0; c < 8; ++c) acc[c] = f32x4{0.f, 0.f, 0.f, 0.f};
        #pragma unroll
        for (int ks = 0; ks < 4; ++ks) {
            const s16x8 ha = *(const s16x8*)(ldsHb + ((hbase + ((u32)ks << 6)) ^ hswz));
            #pragma unroll
            for (int c = 0; c < 8; ++c) {
                const s16x8 bf = *(const s16x8*)(wp2 + ((size_t)((c << 6) + ks) << 9));
                acc[c] = __builtin_amdgcn_mfma_f32_16x16x32_bf16(ha, bf, acc[c], 0, 0, 0);
            }
        }
        // store into owner-contiguous col-major stripes: block (r, o=nt>>1, h), [32c][32r] bf16
        #pragma unroll
        for (int c = 0; c < 8; ++c) {
            const int nt = (np << 3) + c;
            const int o = nt >> 1;
            const int sc2 = ((nt & 1) << 4) + l15;
            const u32 off = (u32)((sc2 << 6) + (mt << 5) + (kg << 3));
            u64 pk = (u64)((u32)f2bf(acc[c][0]) | ((u32)f2bf(acc[c][1]) << 16)) |
                     ((u64)((u32)f2bf(acc[c][2]) | ((u32)f2bf(acc[c][3]) << 16)) << 32);
            agent_st64((u64*)(kprod + (size_t)((o << 4) + h) * 2048 + off), pk);
        }
        __syncthreads();                      // drains vmcnt: partials visible
        if (tid == 0) agent_st(fl1 + (h << 6), (u32)(s + 1));

        // ================= owner: reduce 16 stripes, RK4 update =================
        if (tid < 16) {
            const u32 tgt = (u32)(s + 1);
            while (agent_ld(fl1 + (tid << 6)) < tgt) __builtin_amdgcn_s_sleep(1);
        }
        __syncthreads();
        float s0 = 0.f, s1 = 0.f;
        {
            const u32* kb = (const u32*)kown;
            #pragma unroll
            for (int p = 0; p < 16; ++p) {
                const u32 v = agent_ld(kb + (p << 9) + tid);
                s0 += bf2f(v & 0xffffu);
                s1 += bf2f(v >> 16);
            }
        }
        const int step = s >> 2, sub = s & 3;
        if (sub == 0) {
            dt0 = tt[(step + 1) * Bn + brow0] - tt[step * Bn + brow0];
            dt1 = tt[(step + 1) * Bn + brow1] - tt[step * Bn + brow1];
        }
        const float k0 = dt0 * (s0 + b2c), k1 = dt1 * (s1 + b2c);
        float yin0, yin1;
        if (sub == 0)      { ks0 = k0;        ks1 = k1;        yin0 = ys0 + 0.5f * k0; yin1 = ys1 + 0.5f * k1; }
        else if (sub == 1) { ks0 += 2.f * k0; ks1 += 2.f * k1; yin0 = ys0 + 0.5f * k0; yin1 = ys1 + 0.5f * k1; }
        else if (sub == 2) { ks0 += 2.f * k0; ks1 += 2.f * k1; yin0 = ys0 + k0;        yin1 = ys1 + k1; }
        else {
            ks0 += k0; ks1 += k1;
            ys0 += ks0 * (1.f / 6.f); ys1 += ks1 * (1.f / 6.f);
            yin0 = ys0; yin1 = ys1;
            out[((step + 1) * Bn + brow0) * Dn + colg] = ys0;
            out[((step + 1) * Bn + brow1) * Dn + colg] = ys1;
        }
        if (s < 251) {
            // broadcast next yin: row-major [32][512] bf16, u32 = col-pair
            const u32 my = (u32)f2bf(yin0) | ((u32)f2bf(yin1) << 16);
            const u32 pu = (u32)__shfl_xor((int)my, 16, 64);
            u32 word; int rowsel;
            if ((sc & 1) == 0) { word = (my & 0xffffu) | (pu << 16);       rowsel = 2 * rp; }
            else               { word = (pu >> 16) | (my & 0xffff0000u);   rowsel = 2 * rp + 1; }
            agent_st(ybr + (rowsel << 8) + ((colg >> 1)), word);
            __syncthreads();
            if (tid == 0) agent_st(fl2 + (h << 6), (u32)(s + 1));
        }
    }
}

// ---------------- fallback: round-1 kernel (32 WGs) ----------------
__launch_bounds__(512, 2)
__global__ void ode_rk4_fb(const float* __restrict__ y0, const float* __restrict__ tt,
                           const float* __restrict__ b1, const float* __restrict__ b2,
                           const u16* __restrict__ w1p, const u16* __restrict__ w2p,
                           float* __restrict__ out) {
    __shared__ u16 lds_ys[16 * Dn];
    __shared__ u16 lds_hid[16 * Hn];
    __shared__ float lds_dt[16];
    const int tid = threadIdx.x;
    const int w = tid >> 6, lane = tid & 63, l15 = lane & 15, kgrp = lane >> 4;
    const int row0 = blockIdx.x << 4;
    float yreg[4][4], ksum[4][4], kk[4][4];
    float b1v[16], b2v[4], dtv[4];
    #pragma unroll
    for (int nt = 0; nt < 16; ++nt) b1v[nt] = b1[(w << 8) + (nt << 4) + l15];
    #pragma unroll
    for (int c = 0; c < 4; ++c) b2v[c] = b2[(w << 6) + (c << 4) + l15];
    #pragma unroll
    for (int c = 0; c < 4; ++c)
        #pragma unroll
        for (int j = 0; j < 4; ++j) {
            const int rr = (kgrp << 2) + j;
            const int col = (w << 6) + (c << 4) + l15;
            const float v = y0[(row0 + rr) * Dn + col];
            yreg[c][j] = v; ksum[c][j] = 0.f; kk[c][j] = 0.f;
            out[(row0 + rr) * Dn + col] = v;
        }
    const u16* wv1 = w1p + ((w << 4) * (16 * 512)) + (lane << 3);
    const u16* wv2 = w2p + ((w << 2) * (64 * 512)) + (lane << 3);
    const int arow = l15;
    const unsigned swzA = (unsigned)((arow & 7) << 3);
    for (int step = 0; step < Tn - 1; ++step) {
        if (tid < 16)
            lds_dt[tid] = tt[(step + 1) * Bn + row0 + tid] - tt[step * Bn + row0 + tid];
        #pragma unroll 1
        for (int s = 0; s < 4; ++s) {
            const float ci = (s == 3) ? 1.0f : ((s == 0) ? 0.0f : 0.5f);
            #pragma unroll
            for (int c = 0; c < 4; ++c)
                #pragma unroll
                for (int j = 0; j < 4; ++j) {
                    const int rr = (kgrp << 2) + j;
                    const int col = (w << 6) + (c << 4) + l15;
                    lds_ys[(unsigned)((rr << 9) + col) ^ (unsigned)((rr & 7) << 3)] =
                        f2bf(yreg[c][j] + ci * kk[c][j]);
                }
            __syncthreads();
            if (s == 0) {
                #pragma unroll
                for (int j = 0; j < 4; ++j) dtv[j] = lds_dt[(kgrp << 2) + j];
            }
            f32x4 acc[16];
            #pragma unroll
            for (int nt = 0; nt < 16; ++nt)
                #pragma unroll
                for (int j = 0; j < 4; ++j) acc[nt][j] = b1v[nt];
            #pragma unroll 2
            for (int kt = 0; kt < 16; ++kt) {
                const unsigned ia = ((unsigned)((arow << 9) + (kt << 5) + (kgrp << 3))) ^ swzA;
                const s16x8 a = *(const s16x8*)&lds_ys[ia];
                #pragma unroll
                for (int nt = 0; nt < 16; ++nt) {
                    const s16x8 bfrag = *(const s16x8*)&wv1[nt * 8192 + kt * 512];
                    acc[nt] = __builtin_amdgcn_mfma_f32_16x16x32_bf16(a, bfrag, acc[nt], 0, 0, 0);
                }
            }
            #pragma unroll
            for (int nt = 0; nt < 16; ++nt)
                #pragma unroll
                for (int j = 0; j < 4; ++j) {
                    const int rr = (kgrp << 2) + j;
                    const int col = (w << 8) + (nt << 4) + l15;
                    lds_hid[(unsigned)((rr << 11) + col) ^ (unsigned)((rr & 7) << 3)] =
                        f2bf(tanh_fast(acc[nt][j]));
                }
            __syncthreads();
            f32x4 acc2[4];
            #pragma unroll
            for (int c = 0; c < 4; ++c)
                #pragma unroll
                for (int j = 0; j < 4; ++j) acc2[c][j] = 0.f;
            #pragma unroll 2
            for (int kt = 0; kt < 64; ++kt) {
                const unsigned ia = ((unsigned)((arow << 11) + (kt << 5) + (kgrp << 3))) ^ swzA;
                const s16x8 a = *(const s16x8*)&lds_hid[ia];
                #pragma unroll
                for (int c = 0; c < 4; ++c) {
                    const s16x8 bfrag = *(const s16x8*)&wv2[c * 32768 + kt * 512];
                    acc2[c] = __builtin_amdgcn_mfma_f32_16x16x32_bf16(a, bfrag, acc2[c], 0, 0, 0);
                }
            }
            const float wq = (s == 0 || s == 3) ? 1.0f : 2.0f;
            #pragma unroll
            for (int c = 0; c < 4; ++c)
                #pragma unroll
                for (int j = 0; j < 4; ++j) {
                    const float kv = dtv[j] * (acc2[c][j] + b2v[c]);
                    kk[c][j] = kv;
                    ksum[c][j] = (s == 0) ? kv : ksum[c][j] + wq * kv;
                }
        }
        #pragma unroll
        for (int c = 0; c < 4; ++c)
            #pragma unroll
            for (int j = 0; j < 4; ++j) {
                const int rr = (kgrp << 2) + j;
                const int col = (w << 6) + (c << 4) + l15;
                yreg[c][j] += ksum[c][j] * (1.0f / 6.0f);
                out[((step + 1) * Bn + row0 + rr) * Dn + col] = yreg[c][j];
            }
    }
}

extern "C" void kernel_launch(void* const* d_in, const int* in_sizes, int n_in,
                              void* d_out, int out_size, void* d_ws, size_t ws_size,
                              hipStream_t stream) {
    const float* y0 = (const float*)d_in[0];
    const float* tt = (const float*)d_in[1];
    const float* W1 = (const float*)d_in[2];
    const float* b1 = (const float*)d_in[3];
    const float* W2 = (const float*)d_in[4];
    const float* b2 = (const float*)d_in[5];
    float* out = (float*)d_out;
    char* ws = (char*)d_ws;

    const size_t sz_fl = (size_t)256 * 256;                 // 64KB per flag array
    const size_t sz_w = (size_t)Dn * Hn * 2;                // 2MB each
    const size_t sz_ybuf = (size_t)CH * 32 * 512 * 2;       // 512KB
    const size_t sz_kpart = (size_t)CH * 16 * 16 * 2048;    // 8MB
    const size_t needed = 2 * sz_fl + 2 * sz_w + sz_ybuf + sz_kpart + 4096;

    u32* flags1 = (u32*)ws;
    u32* flags2 = (u32*)(ws + sz_fl);
    u16* w1p = (u16*)(ws + 2 * sz_fl);
    u16* w2p = (u16*)(ws + 2 * sz_fl + sz_w);
    u16* ybuf = (u16*)(ws + 2 * sz_fl + 2 * sz_w);
    u16* kpart = (u16*)(ws + 2 * sz_fl + 2 * sz_w + sz_ybuf);

    if (ws_size >= needed) {
        hipMemsetAsync(ws, 0, 2 * sz_fl, stream);
        pack_w<<<4096, 256, 0, stream>>>(W1, W2, w1p, w2p);
        void* args[] = {&y0, &tt, &b1, &b2, &w1p, &w2p, &out, &ybuf, &kpart, &flags1, &flags2};
        hipLaunchCooperativeKernel((void*)ode_v3, dim3(256), dim3(512), args, 0, stream);
    } else {
        u16* f1 = (u16*)ws;
        u16* f2 = f1 + (size_t)Dn * Hn;
        pack_w<<<4096, 256, 0, stream>>>(W1, W2, f1, f2);
        ode_rk4_fb<<<32, 512, 0, stream>>>(y0, tt, b1, b2, f1, f2, out);
    }
}

// Round 5
// 4590.467 us; speedup vs baseline: 1.7392x; 1.7392x over previous
//
#include <hip/hip_runtime.h>

#define Tn 64
#define Bn 512
#define Dn 512
#define Hn 2048
#define CH 16   // batch chunks, M=32 rows each
#define SL 16   // H slices, 128 cols each

typedef __attribute__((ext_vector_type(8))) short s16x8;
typedef __attribute__((ext_vector_type(4))) float f32x4;
typedef __attribute__((ext_vector_type(4))) unsigned int u32x4;
typedef unsigned int u32;
typedef unsigned long long u64;
typedef unsigned short u16;

__device__ __forceinline__ u16 f2bf(float f) {
    u32 u = __builtin_bit_cast(u32, f);
    return (u16)((u + 0x7fffu + ((u >> 16) & 1u)) >> 16);
}
__device__ __forceinline__ float bf2f(u32 v) {
    return __builtin_bit_cast(float, v << 16);
}
__device__ __forceinline__ float tanh_fast(float x) {
    float e = __builtin_amdgcn_exp2f(x * 2.885390081777927f);
    return 1.0f - 2.0f * __builtin_amdgcn_rcpf(e + 1.0f);
}
__device__ __forceinline__ u32 agent_ld(const u32* p) {
    return __hip_atomic_load((u32*)p, __ATOMIC_RELAXED, __HIP_MEMORY_SCOPE_AGENT);
}
__device__ __forceinline__ void agent_st(u32* p, u32 v) {
    __hip_atomic_store(p, v, __ATOMIC_RELAXED, __HIP_MEMORY_SCOPE_AGENT);
}

// Pack W1 (512x2048) and W2 (2048x512), f32 row-major -> bf16 MFMA-B-fragment order.
__global__ void pack_w(const float* __restrict__ W1, const float* __restrict__ W2,
                       u16* __restrict__ w1p, u16* __restrict__ w2p) {
    const int i = blockIdx.x * 256 + threadIdx.x;
    const int e = i & 7;
    const int lane = (i >> 3) & 63;
    const int krem = ((lane >> 4) << 3) + e;
    const int ncol = lane & 15;
    {   // W1: K=512 (16 ktiles), N=2048 (128 ntiles)
        const int kt = (i >> 9) & 15, nt = i >> 13;
        const int k = (kt << 5) + krem, n = (nt << 4) + ncol;
        w1p[i] = f2bf(W1[k * Hn + n]);
    }
    {   // W2: K=2048 (64 ktiles), N=512 (32 ntiles)
        const int kt = (i >> 9) & 63, nt = i >> 15;
        const int k = (kt << 5) + krem, n = (nt << 4) + ncol;
        w2p[i] = f2bf(W2[k * Dn + n]);
    }
}

// 256 WGs = 16 chunks x 16 slices. bid = r*16 + h (slice -> XCD affinity).
// v5: all exchange traffic is sc0 sc1 nt (device-coherent, L2 non-allocating)
// so the 4MB weight set stays L2-resident; flags packed one 64B line per chunk.
__launch_bounds__(512, 2)
__global__ void ode_v5(const float* __restrict__ y0, const float* __restrict__ tt,
                       const float* __restrict__ b1, const float* __restrict__ b2,
                       const u16* __restrict__ w1p, const u16* __restrict__ w2p,
                       float* __restrict__ out, u16* __restrict__ ybuf,
                       u16* __restrict__ kpart, u32* __restrict__ flags1,
                       u32* __restrict__ flags2) {
    __shared__ u16 lds_A[32 * 512];    // 32KB, row stride 1024B, xor-swz ((row&7)<<4)
    __shared__ u16 lds_H[32 * 128];    // 8KB,  row stride 256B,  xor-swz ((row&7)<<4)
    char* ldsAb = (char*)lds_A;
    char* ldsHb = (char*)lds_H;

    const int tid = threadIdx.x;
    const int w = tid >> 6, lane = tid & 63, l15 = lane & 15, kg = lane >> 4;
    const int bid = blockIdx.x;
    const int r = bid >> 4, h = bid & 15;

    // owner/reducer mapping: col sc in slice, rowpair rp
    const int sc = tid >> 4;                 // 0..31
    const int rp = tid & 15;                 // 0..15
    const int colg = (h << 5) + sc;
    const int brow0 = (r << 5) + 2 * rp, brow1 = brow0 + 1;
    const float b2c = b2[colg];
    float ys0 = y0[brow0 * Dn + colg];
    float ys1 = y0[brow1 * Dn + colg];
    __builtin_nontemporal_store(ys0, &out[brow0 * Dn + colg]);
    __builtin_nontemporal_store(ys1, &out[brow1 * Dn + colg]);
    float ks0 = 0.f, ks1 = 0.f, dt0 = 0.f, dt1 = 0.f;

    // GEMM wave constants
    const int mt = w & 1;
    const int np = w >> 1;
    const float bia0 = b1[(h << 7) + ((np << 1) << 4) + l15];
    const float bia1 = b1[(h << 7) + (((np << 1) + 1) << 4) + l15];
    const u16* wp1 = w1p + ((size_t)((h << 3) + (np << 1)) << 4) * 512 + (lane << 3);
    const u16* wp2 = w2p + ((size_t)(np << 3) * 64 + (h << 2)) * 512 + (lane << 3);

    const u32 arow = (u32)((mt << 4) + l15);
    const u32 abase = arow * 1024u + ((u32)kg << 4);
    const u32 aswz = (arow & 7u) << 4;
    const u32 hbase = arow * 256u + ((u32)kg << 4);
    const u32 hswz = aswz;

    u32* ybr = (u32*)(ybuf + (size_t)r * 32 * 512);
    const u32* kown = (const u32*)((const char*)kpart + (size_t)(((r << 4) + h) << 4) * 2048);
    char* kprod = (char*)kpart + (size_t)(r << 8) * 2048;   // + (o*16+h)*2048
    u32* fl1p = flags1 + (r << 6);   // 16 packed dwords, one 64B line per chunk
    u32* fl2p = flags2 + (r << 6);

    #pragma unroll 1
    for (int s = 0; s < 252; ++s) {
        // ================= stage A: yin -> lds_A =================
        if (s == 0) {
            const float4* y0c = (const float4*)(y0 + (size_t)(r << 5) * Dn);
            #pragma unroll
            for (int it = 0; it < 8; ++it) {
                const int idx = (it << 9) + tid;          // over [32 rows][128 f4]
                const float4 v = y0c[idx];
                const u32 row = (u32)idx >> 7;
                u64 pk = (u64)((u32)f2bf(v.x) | ((u32)f2bf(v.y) << 16)) |
                         ((u64)((u32)f2bf(v.z) | ((u32)f2bf(v.w) << 16)) << 32);
                const u32 dst = (row * 1024u + ((u32)(idx & 127) << 3)) ^ ((row & 7u) << 4);
                *(u64*)(ldsAb + dst) = pk;
            }
        } else {
            if (tid < 16) {
                const u32 tgt = (u32)s;
                while (agent_ld(fl2p + tid) < tgt) __builtin_amdgcn_s_sleep(1);
            }
            __syncthreads();
            // bulk nt read of yin [32][256 u32]: 4 x dwordx4 per thread
            u32x4 q[4];
            const u32 vo = (u32)(tid << 4);
            asm volatile("global_load_dwordx4 %0, %1, %2 sc0 sc1 nt"
                         : "=v"(q[0]) : "v"(vo), "s"(ybr) : "memory");
            asm volatile("global_load_dwordx4 %0, %1, %2 sc0 sc1 nt"
                         : "=v"(q[1]) : "v"(vo + 8192u), "s"(ybr) : "memory");
            asm volatile("global_load_dwordx4 %0, %1, %2 sc0 sc1 nt"
                         : "=v"(q[2]) : "v"(vo + 16384u), "s"(ybr) : "memory");
            asm volatile("global_load_dwordx4 %0, %1, %2 sc0 sc1 nt"
                         : "=v"(q[3]) : "v"(vo + 24576u), "s"(ybr) : "memory");
            asm volatile("s_waitcnt vmcnt(0)"
                         : "+v"(q[0]), "+v"(q[1]), "+v"(q[2]), "+v"(q[3]) :: "memory");
            #pragma unroll
            for (int i2 = 0; i2 < 4; ++i2) {
                const u32 idx = ((u32)i2 << 11) + ((u32)tid << 2);  // u32 index
                const u32 row = idx >> 8;
                const u32 dst = (idx << 2) ^ ((row & 7u) << 4);
                *(u32x4*)(ldsAb + dst) = q[i2];
            }
        }
        __syncthreads();

        // ================= GEMM1: hid = tanh(A @ W1slice + b1) =================
        f32x4 a1[2];
        a1[0] = f32x4{bia0, bia0, bia0, bia0};
        a1[1] = f32x4{bia1, bia1, bia1, bia1};
        #pragma unroll
        for (int kt = 0; kt < 16; ++kt) {
            const s16x8 a = *(const s16x8*)(ldsAb + ((abase + ((u32)kt << 6)) ^ aswz));
            const s16x8 b0 = *(const s16x8*)(wp1 + ((size_t)kt << 9));
            const s16x8 b1f = *(const s16x8*)(wp1 + ((size_t)(16 + kt) << 9));
            a1[0] = __builtin_amdgcn_mfma_f32_16x16x32_bf16(a, b0, a1[0], 0, 0, 0);
            a1[1] = __builtin_amdgcn_mfma_f32_16x16x32_bf16(a, b1f, a1[1], 0, 0, 0);
        }
        #pragma unroll
        for (int n = 0; n < 2; ++n) {
            #pragma unroll
            for (int j = 0; j < 4; ++j) {
                const u32 row = (u32)((mt << 4) + (kg << 2) + j);
                const u32 col = (u32)((((np << 1) + n) << 4) + l15);
                const u32 bo = (row * 256u + (col << 1)) ^ ((row & 7u) << 4);
                *(u16*)(ldsHb + bo) = f2bf(tanh_fast(a1[n][j]));
            }
        }
        __syncthreads();

        // ================= GEMM2: partial = hid @ W2slice (K=128) =================
        f32x4 acc[8];
        #pragma unroll
        for (int c = 0; c < 8; ++c) acc[c] = f32x4{0.f, 0.f, 0.f, 0.f};
        #pragma unroll
        for (int ks = 0; ks < 4; ++ks) {
            const s16x8 ha = *(const s16x8*)(ldsHb + ((hbase + ((u32)ks << 6)) ^ hswz));
            #pragma unroll
            for (int c = 0; c < 8; ++c) {
                const s16x8 bf = *(const s16x8*)(wp2 + ((size_t)((c << 6) + ks) << 9));
                acc[c] = __builtin_amdgcn_mfma_f32_16x16x32_bf16(ha, bf, acc[c], 0, 0, 0);
            }
        }
        // nt stores into owner-contiguous col-major stripes (r, o=nt>>1, h): [32c][32r] bf16
        #pragma unroll
        for (int c = 0; c < 8; ++c) {
            const int nt = (np << 3) + c;
            const int o = nt >> 1;
            const int sc2 = ((nt & 1) << 4) + l15;
            const u32 off = (u32)((sc2 << 6) + (mt << 5) + (kg << 3));
            u64 pk = (u64)((u32)f2bf(acc[c][0]) | ((u32)f2bf(acc[c][1]) << 16)) |
                     ((u64)((u32)f2bf(acc[c][2]) | ((u32)f2bf(acc[c][3]) << 16)) << 32);
            void* pa = kprod + (size_t)((o << 4) + h) * 2048 + off;
            asm volatile("global_store_dwordx2 %0, %1, off sc0 sc1 nt"
                         :: "v"(pa), "v"(pk) : "memory");
        }
        asm volatile("s_waitcnt vmcnt(0)" ::: "memory");
        __syncthreads();                      // all partials globally visible
        if (tid == 0) agent_st(fl1p + h, (u32)(s + 1));

        // ================= owner: reduce 16 stripes, RK4 update =================
        if (tid < 16) {
            const u32 tgt = (u32)(s + 1);
            while (agent_ld(fl1p + tid) < tgt) __builtin_amdgcn_s_sleep(1);
        }
        __syncthreads();
        float s0 = 0.f, s1 = 0.f;
        {
            const u32 vo2 = (u32)(tid << 2);
            u32 t0, t1, t2, t3, t4, t5, t6, t7;
#define NT_LD(dst, P) asm volatile("global_load_dword %0, %1, %2 sc0 sc1 nt" \
        : "=v"(dst) : "v"(vo2 + ((u32)(P) << 11)), "s"(kown) : "memory")
#define ACC8() do { \
        s0 += bf2f(t0 & 0xffffu); s1 += bf2f(t0 >> 16); \
        s0 += bf2f(t1 & 0xffffu); s1 += bf2f(t1 >> 16); \
        s0 += bf2f(t2 & 0xffffu); s1 += bf2f(t2 >> 16); \
        s0 += bf2f(t3 & 0xffffu); s1 += bf2f(t3 >> 16); \
        s0 += bf2f(t4 & 0xffffu); s1 += bf2f(t4 >> 16); \
        s0 += bf2f(t5 & 0xffffu); s1 += bf2f(t5 >> 16); \
        s0 += bf2f(t6 & 0xffffu); s1 += bf2f(t6 >> 16); \
        s0 += bf2f(t7 & 0xffffu); s1 += bf2f(t7 >> 16); } while (0)
            NT_LD(t0, 0); NT_LD(t1, 1); NT_LD(t2, 2); NT_LD(t3, 3);
            NT_LD(t4, 4); NT_LD(t5, 5); NT_LD(t6, 6); NT_LD(t7, 7);
            asm volatile("s_waitcnt vmcnt(0)"
                         : "+v"(t0), "+v"(t1), "+v"(t2), "+v"(t3),
                           "+v"(t4), "+v"(t5), "+v"(t6), "+v"(t7) :: "memory");
            ACC8();
            NT_LD(t0, 8); NT_LD(t1, 9); NT_LD(t2, 10); NT_LD(t3, 11);
            NT_LD(t4, 12); NT_LD(t5, 13); NT_LD(t6, 14); NT_LD(t7, 15);
            asm volatile("s_waitcnt vmcnt(0)"
                         : "+v"(t0), "+v"(t1), "+v"(t2), "+v"(t3),
                           "+v"(t4), "+v"(t5), "+v"(t6), "+v"(t7) :: "memory");
            ACC8();
#undef NT_LD
#undef ACC8
        }
        const int step = s >> 2, sub = s & 3;
        if (sub == 0) {
            dt0 = tt[(step + 1) * Bn + brow0] - tt[step * Bn + brow0];
            dt1 = tt[(step + 1) * Bn + brow1] - tt[step * Bn + brow1];
        }
        const float k0 = dt0 * (s0 + b2c), k1 = dt1 * (s1 + b2c);
        float yin0, yin1;
        if (sub == 0)      { ks0 = k0;        ks1 = k1;        yin0 = ys0 + 0.5f * k0; yin1 = ys1 + 0.5f * k1; }
        else if (sub == 1) { ks0 += 2.f * k0; ks1 += 2.f * k1; yin0 = ys0 + 0.5f * k0; yin1 = ys1 + 0.5f * k1; }
        else if (sub == 2) { ks0 += 2.f * k0; ks1 += 2.f * k1; yin0 = ys0 + k0;        yin1 = ys1 + k1; }
        else {
            ks0 += k0; ks1 += k1;
            ys0 += ks0 * (1.f / 6.f); ys1 += ks1 * (1.f / 6.f);
            yin0 = ys0; yin1 = ys1;
            __builtin_nontemporal_store(ys0, &out[((step + 1) * Bn + brow0) * Dn + colg]);
            __builtin_nontemporal_store(ys1, &out[((step + 1) * Bn + brow1) * Dn + colg]);
        }
        if (s < 251) {
            // broadcast next yin: row-major [32][512] bf16, u32 = col-pair
            const u32 my = (u32)f2bf(yin0) | ((u32)f2bf(yin1) << 16);
            const u32 pu = (u32)__shfl_xor((int)my, 16, 64);
            u32 word; int rowsel;
            if ((sc & 1) == 0) { word = (my & 0xffffu) | (pu << 16);       rowsel = 2 * rp; }
            else               { word = (pu >> 16) | (my & 0xffff0000u);   rowsel = 2 * rp + 1; }
            u32* baddr = ybr + (rowsel << 8) + (colg >> 1);
            asm volatile("global_store_dword %0, %1, off sc0 sc1 nt"
                         :: "v"(baddr), "v"(word) : "memory");
            asm volatile("s_waitcnt vmcnt(0)" ::: "memory");
            __syncthreads();
            if (tid == 0) agent_st(fl2p + h, (u32)(s + 1));
        }
    }
}

// ---------------- fallback: round-1 kernel (32 WGs) ----------------
__launch_bounds__(512, 2)
__global__ void ode_rk4_fb(const float* __restrict__ y0, const float* __restrict__ tt,
                           const float* __restrict__ b1, const float* __restrict__ b2,
                           const u16* __restrict__ w1p, const u16* __restrict__ w2p,
                           float* __restrict__ out) {
    __shared__ u16 lds_ys[16 * Dn];
    __shared__ u16 lds_hid[16 * Hn];
    __shared__ float lds_dt[16];
    const int tid = threadIdx.x;
    const int w = tid >> 6, lane = tid & 63, l15 = lane & 15, kgrp = lane >> 4;
    const int row0 = blockIdx.x << 4;
    float yreg[4][4], ksum[4][4], kk[4][4];
    float b1v[16], b2v[4], dtv[4];
    #pragma unroll
    for (int nt = 0; nt < 16; ++nt) b1v[nt] = b1[(w << 8) + (nt << 4) + l15];
    #pragma unroll
    for (int c = 0; c < 4; ++c) b2v[c] = b2[(w << 6) + (c << 4) + l15];
    #pragma unroll
    for (int c = 0; c < 4; ++c)
        #pragma unroll
        for (int j = 0; j < 4; ++j) {
            const int rr = (kgrp << 2) + j;
            const int col = (w << 6) + (c << 4) + l15;
            const float v = y0[(row0 + rr) * Dn + col];
            yreg[c][j] = v; ksum[c][j] = 0.f; kk[c][j] = 0.f;
            out[(row0 + rr) * Dn + col] = v;
        }
    const u16* wv1 = w1p + ((w << 4) * (16 * 512)) + (lane << 3);
    const u16* wv2 = w2p + ((w << 2) * (64 * 512)) + (lane << 3);
    const int arow = l15;
    const unsigned swzA = (unsigned)((arow & 7) << 3);
    for (int step = 0; step < Tn - 1; ++step) {
        if (tid < 16)
            lds_dt[tid] = tt[(step + 1) * Bn + row0 + tid] - tt[step * Bn + row0 + tid];
        #pragma unroll 1
        for (int s = 0; s < 4; ++s) {
            const float ci = (s == 3) ? 1.0f : ((s == 0) ? 0.0f : 0.5f);
            #pragma unroll
            for (int c = 0; c < 4; ++c)
                #pragma unroll
                for (int j = 0; j < 4; ++j) {
                    const int rr = (kgrp << 2) + j;
                    const int col = (w << 6) + (c << 4) + l15;
                    lds_ys[(unsigned)((rr << 9) + col) ^ (unsigned)((rr & 7) << 3)] =
                        f2bf(yreg[c][j] + ci * kk[c][j]);
                }
            __syncthreads();
            if (s == 0) {
                #pragma unroll
                for (int j = 0; j < 4; ++j) dtv[j] = lds_dt[(kgrp << 2) + j];
            }
            f32x4 acc[16];
            #pragma unroll
            for (int nt = 0; nt < 16; ++nt)
                #pragma unroll
                for (int j = 0; j < 4; ++j) acc[nt][j] = b1v[nt];
            #pragma unroll 2
            for (int kt = 0; kt < 16; ++kt) {
                const unsigned ia = ((unsigned)((arow << 9) + (kt << 5) + (kgrp << 3))) ^ swzA;
                const s16x8 a = *(const s16x8*)&lds_ys[ia];
                #pragma unroll
                for (int nt = 0; nt < 16; ++nt) {
                    const s16x8 bfrag = *(const s16x8*)&wv1[nt * 8192 + kt * 512];
                    acc[nt] = __builtin_amdgcn_mfma_f32_16x16x32_bf16(a, bfrag, acc[nt], 0, 0, 0);
                }
            }
            #pragma unroll
            for (int nt = 0; nt < 16; ++nt)
                #pragma unroll
                for (int j = 0; j < 4; ++j) {
                    const int rr = (kgrp << 2) + j;
                    const int col = (w << 8) + (nt << 4) + l15;
                    lds_hid[(unsigned)((rr << 11) + col) ^ (unsigned)((rr & 7) << 3)] =
                        f2bf(tanh_fast(acc[nt][j]));
                }
            __syncthreads();
            f32x4 acc2[4];
            #pragma unroll
            for (int c = 0; c < 4; ++c)
                #pragma unroll
                for (int j = 0; j < 4; ++j) acc2[c][j] = 0.f;
            #pragma unroll 2
            for (int kt = 0; kt < 64; ++kt) {
                const unsigned ia = ((unsigned)((arow << 11) + (kt << 5) + (kgrp << 3))) ^ swzA;
                const s16x8 a = *(const s16x8*)&lds_hid[ia];
                #pragma unroll
                for (int c = 0; c < 4; ++c) {
                    const s16x8 bfrag = *(const s16x8*)&wv2[c * 32768 + kt * 512];
                    acc2[c] = __builtin_amdgcn_mfma_f32_16x16x32_bf16(a, bfrag, acc2[c], 0, 0, 0);
                }
            }
            const float wq = (s == 0 || s == 3) ? 1.0f : 2.0f;
            #pragma unroll
            for (int c = 0; c < 4; ++c)
                #pragma unroll
                for (int j = 0; j < 4; ++j) {
                    const float kv = dtv[j] * (acc2[c][j] + b2v[c]);
                    kk[c][j] = kv;
                    ksum[c][j] = (s == 0) ? kv : ksum[c][j] + wq * kv;
                }
        }
        #pragma unroll
        for (int c = 0; c < 4; ++c)
            #pragma unroll
            for (int j = 0; j < 4; ++j) {
                const int rr = (kgrp << 2) + j;
                const int col = (w << 6) + (c << 4) + l15;
                yreg[c][j] += ksum[c][j] * (1.0f / 6.0f);
                out[((step + 1) * Bn + row0 + rr) * Dn + col] = yreg[c][j];
            }
    }
}

extern "C" void kernel_launch(void* const* d_in, const int* in_sizes, int n_in,
                              void* d_out, int out_size, void* d_ws, size_t ws_size,
                              hipStream_t stream) {
    const float* y0 = (const float*)d_in[0];
    const float* tt = (const float*)d_in[1];
    const float* W1 = (const float*)d_in[2];
    const float* b1 = (const float*)d_in[3];
    const float* W2 = (const float*)d_in[4];
    const float* b2 = (const float*)d_in[5];
    float* out = (float*)d_out;
    char* ws = (char*)d_ws;

    const size_t sz_fl = (size_t)256 * 256;                 // flag arrays (16 chunks x 256B)
    const size_t sz_w = (size_t)Dn * Hn * 2;                // 2MB each
    const size_t sz_ybuf = (size_t)CH * 32 * 512 * 2;       // 512KB
    const size_t sz_kpart = (size_t)CH * 16 * 16 * 2048;    // 8MB
    const size_t needed = 2 * sz_fl + 2 * sz_w + sz_ybuf + sz_kpart + 4096;

    u32* flags1 = (u32*)ws;
    u32* flags2 = (u32*)(ws + sz_fl);
    u16* w1p = (u16*)(ws + 2 * sz_fl);
    u16* w2p = (u16*)(ws + 2 * sz_fl + sz_w);
    u16* ybuf = (u16*)(ws + 2 * sz_fl + 2 * sz_w);
    u16* kpart = (u16*)(ws + 2 * sz_fl + 2 * sz_w + sz_ybuf);

    if (ws_size >= needed) {
        hipMemsetAsync(ws, 0, 2 * sz_fl, stream);
        pack_w<<<4096, 256, 0, stream>>>(W1, W2, w1p, w2p);
        void* args[] = {&y0, &tt, &b1, &b2, &w1p, &w2p, &out, &ybuf, &kpart, &flags1, &flags2};
        hipLaunchCooperativeKernel((void*)ode_v5, dim3(256), dim3(512), args, 0, stream);
    } else {
        u16* f1 = (u16*)ws;
        u16* f2 = f1 + (size_t)Dn * Hn;
        pack_w<<<4096, 256, 0, stream>>>(W1, W2, f1, f2);
        ode_rk4_fb<<<32, 512, 0, stream>>>(y0, tt, b1, b2, f1, f2, out);
    }
}